// Round 3
// baseline (125.533 us; speedup 1.0000x reference)
//
#include <hip/hip_runtime.h>

// ---------------------------------------------------------------------------
// SwitchGLU MoE, round 3: latency-proof pipelined grouped bf16-MFMA GEMMs.
//  - raw s_barrier (NO vmcnt drain) + lgkmcnt(0) asm: loads stay in flight
//  - sched_barrier(0) pins load-issue early (compiler can't sink them)
//  - bijective XOR chunk swizzle: conflict-free LDS read & write
//  - stage2: BM=256, split-K=8, fp32 atomicAdd epilogue
// ---------------------------------------------------------------------------

typedef unsigned short u16;
typedef unsigned int   u32;
typedef u16   u16x8 __attribute__((ext_vector_type(8)));
typedef __bf16 bf16x8 __attribute__((ext_vector_type(8)));
typedef float f32x4 __attribute__((ext_vector_type(4)));

#define NE   8
#define DDIM 768
#define HDIM 2048
#define NTOT 2048

__device__ __forceinline__ u32 pack2(float a, float b) {
  u32 ua = __builtin_bit_cast(u32, a) + 0x8000u;
  u32 ub = __builtin_bit_cast(u32, b) + 0x8000u;
  return __builtin_amdgcn_perm(ub, ua, 0x07060302);  // low u16 = bf16(a)
}
__device__ __forceinline__ u16 f2bf(float f) {
  return (u16)((__builtin_bit_cast(u32, f) + 0x8000u) >> 16);
}
__device__ __forceinline__ uint4 pk4(float4 a, float4 b) {
  uint4 v;
  v.x = pack2(a.x, a.y); v.y = pack2(a.z, a.w);
  v.z = pack2(b.x, b.y); v.w = pack2(b.z, b.w);
  return v;
}
// u16 index of 16B chunk c (0..3) in row r of a [*][32] u16 tile, swizzled
__device__ __forceinline__ int swz(int r, int c) {
  return r * 32 + ((c ^ (r & 3)) << 3);
}
__device__ __forceinline__ bf16x8 frag(const u16* p) {
  return __builtin_bit_cast(bf16x8, *reinterpret_cast<const u16x8*>(p));
}
__device__ __forceinline__ f32x4 mfma(bf16x8 a, bf16x8 b, f32x4 c) {
  return __builtin_amdgcn_mfma_f32_16x16x32_bf16(a, b, c, 0, 0, 0);
}
// end-of-phase: commit LDS ops, workgroup barrier, vmcnt NOT drained
__device__ __forceinline__ void phase_end() {
  __builtin_amdgcn_sched_barrier(0);
  asm volatile("s_waitcnt lgkmcnt(0)" ::: "memory");
  __builtin_amdgcn_s_barrier();
  __builtin_amdgcn_sched_barrier(0);
}

// ---------------------------------------------------------------------------
__global__ void moe_dispatch(const int* __restrict__ idx,
                             int* __restrict__ offs, int* __restrict__ perm) {
  __shared__ int s_cnt[NE];
  __shared__ int s_off[NE + 1];
  __shared__ int s_cur[NE];
  const int tid = threadIdx.x;
  if (tid < NE) { s_cnt[tid] = 0; s_cur[tid] = 0; }
  __syncthreads();
  for (int n = tid; n < NTOT; n += 256) atomicAdd(&s_cnt[idx[n]], 1);
  __syncthreads();
  if (tid == 0) {
    int a = 0;
    for (int e = 0; e < NE; ++e) { s_off[e] = a; a += s_cnt[e]; }
    s_off[NE] = a;
  }
  __syncthreads();
  for (int n = tid; n < NTOT; n += 256) {
    const int e = idx[n];
    perm[s_off[e] + atomicAdd(&s_cur[e], 1)] = n;
  }
  if (tid < NE + 1) offs[tid] = s_off[tid];
}

// ---------------------------------------------------------------------------
// Stage 1: h = silu(X Wg^T) * (X Wu^T).  BM=128, BN=128(G)+128(U), BK=32.
// grid (16, 4, 8), 512 threads = 8 waves as 4M x 2N; wave = 32M x 64N of BOTH.
// ---------------------------------------------------------------------------
__global__ __launch_bounds__(512, 2) void moe_stage1(
    const float* __restrict__ x, const int* __restrict__ perm,
    const int* __restrict__ offs, const float* __restrict__ wg,
    const float* __restrict__ wu, u16* __restrict__ hbuf) {
  const int e = blockIdx.z;
  const int off = offs[e];
  const int cnt = offs[e + 1] - off;
  const int mt = blockIdx.y;
  if (mt * 128 >= cnt) return;
  const int nt = blockIdx.x;  // 0..15

  __shared__ __align__(16) u16 sX[2][128 * 32];
  __shared__ __align__(16) u16 sG[2][128 * 32];
  __shared__ __align__(16) u16 sU[2][128 * 32];

  const int tid = threadIdx.x;
  const int lane = tid & 63;
  const int wv = tid >> 6;
  const int wm = (wv >> 1) * 32;   // 0,32,64,96
  const int wn = (wv & 1) * 64;    // 0,64

  const int sr = tid >> 2;  // 0..127
  const int sc = tid & 3;

  const int trow = perm[min(off + mt * 128 + sr, NTOT - 1)] >> 1;  // TOPK=2
  const float* xrow = x + (size_t)trow * DDIM + sc * 8;
  const float* grow = wg + ((size_t)e * HDIM + nt * 128 + sr) * DDIM + sc * 8;
  const float* urow = wu + ((size_t)e * HDIM + nt * 128 + sr) * DDIM + sc * 8;

  f32x4 aG[2][4] = {};
  f32x4 aU[2][4] = {};
  float4 aX0, aX1, aW0, aW1, aV0, aV1;  // prefetch set A
  float4 bX0, bX1, bW0, bW1, bV0, bV1;  // prefetch set B

#define S1_LOAD(p, kt) do {                                                \
    const float4* q_;                                                      \
    q_ = (const float4*)(xrow + (kt) * 32); p##X0 = q_[0]; p##X1 = q_[1];  \
    q_ = (const float4*)(grow + (kt) * 32); p##W0 = q_[0]; p##W1 = q_[1];  \
    q_ = (const float4*)(urow + (kt) * 32); p##V0 = q_[0]; p##V1 = q_[1];  \
  } while (0)

#define S1_STORE(p, b) do {                                  \
    const int o_ = swz(sr, sc);                              \
    *reinterpret_cast<uint4*>(&sX[b][o_]) = pk4(p##X0, p##X1); \
    *reinterpret_cast<uint4*>(&sG[b][o_]) = pk4(p##W0, p##W1); \
    *reinterpret_cast<uint4*>(&sU[b][o_]) = pk4(p##V0, p##V1); \
  } while (0)

#define S1_COMPUTE(b) do {                                   \
    const int fr_ = lane & 15, kc_ = lane >> 4;              \
    bf16x8 a0_ = frag(&sX[b][swz(wm + fr_, kc_)]);           \
    bf16x8 a1_ = frag(&sX[b][swz(wm + 16 + fr_, kc_)]);      \
    _Pragma("unroll") for (int nj = 0; nj < 4; ++nj) {       \
      bf16x8 g_ = frag(&sG[b][swz(wn + nj * 16 + fr_, kc_)]);\
      bf16x8 u_ = frag(&sU[b][swz(wn + nj * 16 + fr_, kc_)]);\
      aG[0][nj] = mfma(a0_, g_, aG[0][nj]);                  \
      aG[1][nj] = mfma(a1_, g_, aG[1][nj]);                  \
      aU[0][nj] = mfma(a0_, u_, aU[0][nj]);                  \
      aU[1][nj] = mfma(a1_, u_, aU[1][nj]);                  \
    }                                                        \
  } while (0)

  S1_LOAD(a, 0);
  S1_LOAD(b, 1);
  __builtin_amdgcn_sched_barrier(0);
  S1_STORE(a, 0);
  phase_end();

#pragma unroll 1
  for (int kt = 0; kt < 24; kt += 2) {
    if (kt + 2 < 24) S1_LOAD(a, kt + 2);     // prefetch tile kt+2 (set A)
    __builtin_amdgcn_sched_barrier(0);
    S1_COMPUTE(0);                           // consume buf0 = tile kt
    S1_STORE(b, 1);                          // stage tile kt+1 (set B)
    phase_end();
    if (kt + 3 < 24) S1_LOAD(b, kt + 3);     // prefetch tile kt+3 (set B)
    __builtin_amdgcn_sched_barrier(0);
    S1_COMPUTE(1);                           // consume buf1 = tile kt+1
    if (kt + 2 < 24) S1_STORE(a, 0);         // stage tile kt+2 (set A)
    phase_end();
  }

  // epilogue: C/D layout col=lane&15, row=(lane>>4)*4+reg
  const int crow = (lane >> 4) << 2;
  const int ccol = lane & 15;
#pragma unroll
  for (int mi = 0; mi < 2; ++mi) {
#pragma unroll
    for (int ri = 0; ri < 4; ++ri) {
      const int gm = mt * 128 + wm + mi * 16 + crow + ri;
      if (gm < cnt) {
        u16* hb = hbuf + (size_t)(off + gm) * HDIM + nt * 128 + wn;
#pragma unroll
        for (int nj = 0; nj < 4; ++nj) {
          const float g = aG[mi][nj][ri];
          const float u = aU[mi][nj][ri];
          const float h = g / (1.0f + __expf(-g)) * u;
          hb[nj * 16 + ccol] = f2bf(h);
        }
      }
    }
  }
}

// ---------------------------------------------------------------------------
// Stage 2: out[tok,:] += h Wd^T.  BM=256, BN=128, BK=32, split-K=8.
// grid (6, 16, 8): y = ks*2 + mtt. 512 threads = 8 waves 4M x 2N (64x64 each).
// ---------------------------------------------------------------------------
__global__ __launch_bounds__(512, 2) void moe_stage2(
    const u16* __restrict__ hbuf, const int* __restrict__ perm,
    const int* __restrict__ offs, const float* __restrict__ wd,
    float* __restrict__ out) {
  const int e = blockIdx.z;
  const int off = offs[e];
  const int cnt = offs[e + 1] - off;
  const int ks = blockIdx.y >> 1;
  const int mtt = blockIdx.y & 1;
  if (mtt * 256 >= cnt) return;
  const int nt = blockIdx.x;  // 0..5

  __shared__ __align__(16) u16 sA[2][256 * 32];
  __shared__ __align__(16) u16 sB[2][128 * 32];

  const int tid = threadIdx.x;
  const int lane = tid & 63;
  const int wv = tid >> 6;
  const int wm = (wv >> 1) * 64;  // 0,64,128,192
  const int wn = (wv & 1) * 64;   // 0,64

  const int sr = tid >> 2;  // 0..127
  const int sc = tid & 3;

  const u16* hA0 = hbuf +
      (size_t)(off + min(mtt * 256 + sr, cnt - 1)) * HDIM + ks * 256 + sc * 8;
  const u16* hA1 = hbuf +
      (size_t)(off + min(mtt * 256 + sr + 128, cnt - 1)) * HDIM + ks * 256 + sc * 8;
  const float* brow =
      wd + ((size_t)e * DDIM + nt * 128 + sr) * HDIM + ks * 256 + sc * 8;

  f32x4 acc[4][4] = {};
  uint4 aA0, aA1; float4 aB0, aB1;  // set A
  uint4 bA0, bA1; float4 bB0, bB1;  // set B

#define S2_LOAD(p, kt) do {                                                \
    p##A0 = *reinterpret_cast<const uint4*>(hA0 + (kt) * 32);              \
    p##A1 = *reinterpret_cast<const uint4*>(hA1 + (kt) * 32);              \
    const float4* q_ = (const float4*)(brow + (kt) * 32);                  \
    p##B0 = q_[0]; p##B1 = q_[1];                                          \
  } while (0)

#define S2_STORE(p, b) do {                                       \
    *reinterpret_cast<uint4*>(&sA[b][swz(sr, sc)]) = p##A0;       \
    *reinterpret_cast<uint4*>(&sA[b][swz(sr + 128, sc)]) = p##A1; \
    *reinterpret_cast<uint4*>(&sB[b][swz(sr, sc)]) = pk4(p##B0, p##B1); \
  } while (0)

#define S2_COMPUTE(b) do {                                       \
    const int fr_ = lane & 15, kc_ = lane >> 4;                  \
    bf16x8 af_[4], bf_[4];                                       \
    _Pragma("unroll") for (int mi = 0; mi < 4; ++mi)             \
      af_[mi] = frag(&sA[b][swz(wm + mi * 16 + fr_, kc_)]);      \
    _Pragma("unroll") for (int nj = 0; nj < 4; ++nj)             \
      bf_[nj] = frag(&sB[b][swz(wn + nj * 16 + fr_, kc_)]);      \
    _Pragma("unroll") for (int mi = 0; mi < 4; ++mi)             \
      _Pragma("unroll") for (int nj = 0; nj < 4; ++nj)           \
        acc[mi][nj] = mfma(af_[mi], bf_[nj], acc[mi][nj]);       \
  } while (0)

  S2_LOAD(a, 0);
  S2_LOAD(b, 1);
  __builtin_amdgcn_sched_barrier(0);
  S2_STORE(a, 0);
  phase_end();

#pragma unroll 1
  for (int kt = 0; kt < 8; kt += 2) {
    if (kt + 2 < 8) S2_LOAD(a, kt + 2);
    __builtin_amdgcn_sched_barrier(0);
    S2_COMPUTE(0);
    S2_STORE(b, 1);
    phase_end();
    if (kt + 3 < 8) S2_LOAD(b, kt + 3);
    __builtin_amdgcn_sched_barrier(0);
    S2_COMPUTE(1);
    if (kt + 2 < 8) S2_STORE(a, 0);
    phase_end();
  }

  const int crow = (lane >> 4) << 2;
  const int ccol = lane & 15;
#pragma unroll
  for (int mi = 0; mi < 4; ++mi) {
#pragma unroll
    for (int ri = 0; ri < 4; ++ri) {
      const int gm = mtt * 256 + wm + mi * 16 + crow + ri;
      if (gm < cnt) {
        const int t = perm[off + gm];
        float* orow = out + (size_t)t * DDIM + nt * 128 + wn;
#pragma unroll
        for (int nj = 0; nj < 4; ++nj) {
          atomicAdd(&orow[nj * 16 + ccol], acc[mi][nj][ri]);
        }
      }
    }
  }
}

// ---------------------------------------------------------------------------
extern "C" void kernel_launch(void* const* d_in, const int* in_sizes, int n_in,
                              void* d_out, int out_size, void* d_ws, size_t ws_size,
                              hipStream_t stream) {
  const float* x  = (const float*)d_in[0];
  const int* idx  = (const int*)d_in[1];
  const float* wg = (const float*)d_in[2];
  const float* wu = (const float*)d_in[3];
  const float* wd = (const float*)d_in[4];
  float* out = (float*)d_out;

  int* iws = (int*)d_ws;
  int* offs = iws;       // 9 ints
  int* perm = iws + 16;  // 2048 ints
  u16* hbuf = (u16*)((char*)d_ws + 16384);  // 2048*2048 bf16 = 8 MB

  hipMemsetAsync(d_out, 0, (size_t)out_size * sizeof(float), stream);
  moe_dispatch<<<1, 256, 0, stream>>>(idx, offs, perm);
  moe_stage1<<<dim3(16, 4, NE), 512, 0, stream>>>(x, perm, offs, wg, wu, hbuf);
  moe_stage2<<<dim3(6, 16, NE), 512, 0, stream>>>(hbuf, perm, offs, wd, out);
}

// Round 4
// 115.915 us; speedup vs baseline: 1.0830x; 1.0830x over previous
//
#include <hip/hip_runtime.h>

// ---------------------------------------------------------------------------
// SwitchGLU MoE, round 4: global_load_lds staging + minimum-2-phase schedule.
//  - fp32 staged directly to LDS via global_load_lds (16B), no reg round-trip
//  - STAGE(next) issued before COMPUTE(cur); one vmcnt(0)+barrier per phase
//  - conflict-free via pre-swizzled GLOBAL source + same XOR on LDS read
//  - fp32->bf16 conversion after ds_read (VALU overlaps MFMA pipe)
//  - stage2 split-K=2, deterministic fp32 atomicAdd epilogue
// ---------------------------------------------------------------------------

typedef unsigned short u16;
typedef unsigned int   u32;
typedef u16    u16x8 __attribute__((ext_vector_type(8)));
typedef __bf16 bf16x8 __attribute__((ext_vector_type(8)));
typedef float  f32x4 __attribute__((ext_vector_type(4)));

#define NE   8
#define DDIM 768
#define HDIM 2048
#define NTOT 2048

__device__ __forceinline__ u32 pack2(float a, float b) {
  u32 ua = __builtin_bit_cast(u32, a) + 0x8000u;
  u32 ub = __builtin_bit_cast(u32, b) + 0x8000u;
  return __builtin_amdgcn_perm(ub, ua, 0x07060302);  // low u16 = bf16(a)
}
__device__ __forceinline__ u16 f2bf(float f) {
  return (u16)((__builtin_bit_cast(u32, f) + 0x8000u) >> 16);
}
__device__ __forceinline__ bf16x8 cvt8(float4 f0, float4 f1) {
  uint4 v;
  v.x = pack2(f0.x, f0.y); v.y = pack2(f0.z, f0.w);
  v.z = pack2(f1.x, f1.y); v.w = pack2(f1.z, f1.w);
  return __builtin_bit_cast(bf16x8, v);
}
__device__ __forceinline__ bf16x8 fragb(const u16* p) {
  return __builtin_bit_cast(bf16x8, *reinterpret_cast<const u16x8*>(p));
}
__device__ __forceinline__ f32x4 mfma(bf16x8 a, bf16x8 b, f32x4 c) {
  return __builtin_amdgcn_mfma_f32_16x16x32_bf16(a, b, c, 0, 0, 0);
}
// async global->LDS, 16B per lane; LDS dest = wave-uniform base + lane*16
__device__ __forceinline__ void gl16(const void* g, void* l) {
  __builtin_amdgcn_global_load_lds(
      (const __attribute__((address_space(1))) void*)g,
      (__attribute__((address_space(3))) void*)l, 16, 0, 0);
}
// end of phase: drain staged loads + my LDS reads, then barrier
__device__ __forceinline__ void phase_sync() {
  __builtin_amdgcn_sched_barrier(0);
  asm volatile("s_waitcnt vmcnt(0) lgkmcnt(0)" ::: "memory");
  __builtin_amdgcn_s_barrier();
  __builtin_amdgcn_sched_barrier(0);
}

// ---------------------------------------------------------------------------
__global__ void moe_dispatch(const int* __restrict__ idx,
                             int* __restrict__ offs, int* __restrict__ perm) {
  __shared__ int s_cnt[NE];
  __shared__ int s_off[NE + 1];
  __shared__ int s_cur[NE];
  const int tid = threadIdx.x;
  if (tid < NE) { s_cnt[tid] = 0; s_cur[tid] = 0; }
  __syncthreads();
  for (int n = tid; n < NTOT; n += 256) atomicAdd(&s_cnt[idx[n]], 1);
  __syncthreads();
  if (tid == 0) {
    int a = 0;
    for (int e = 0; e < NE; ++e) { s_off[e] = a; a += s_cnt[e]; }
    s_off[NE] = a;
  }
  __syncthreads();
  for (int n = tid; n < NTOT; n += 256) {
    const int e = idx[n];
    perm[s_off[e] + atomicAdd(&s_cur[e], 1)] = n;
  }
  if (tid < NE + 1) offs[tid] = s_off[tid];
}

// ---------------------------------------------------------------------------
// Stage 1: h = silu(X Wg^T) * (X Wu^T).  BM=128, BN=64(G)+64(U), BK=32.
// grid (32, 16, 8), 256 thr = 4 waves (2M x 2N), wave = 64M x 32N of both.
// ---------------------------------------------------------------------------
__global__ __launch_bounds__(256, 2) void moe_stage1(
    const float* __restrict__ x, const int* __restrict__ perm,
    const int* __restrict__ offs, const float* __restrict__ wg,
    const float* __restrict__ wu, u16* __restrict__ hbuf) {
  const int e = blockIdx.z;
  const int off = offs[e];
  const int cnt = offs[e + 1] - off;
  const int mt = blockIdx.y;
  if (mt * 128 >= cnt) return;
  const int nt = blockIdx.x;  // 0..31

  __shared__ __align__(16) float sX[2][128 * 32];
  __shared__ __align__(16) float sG[2][64 * 32];
  __shared__ __align__(16) float sU[2][64 * 32];

  const int tid = threadIdx.x;
  const int lane = tid & 63;
  const int wv = tid >> 6;
  const int wm = (wv >> 1) * 64;  // 0,64
  const int wn = (wv & 1) * 32;   // 0,32

  // ---- staging pointers (per-lane, pre-swizzled global source) ----
  // fp32 rows are 128B = 8 chunks of 16B; lane L of an instr covers
  // (row_in_seg = L>>3, chunk = L&7); global chunk = (L&7) ^ (row&7).
  const int lr = lane >> 3, lc = lane & 7;
  const float* gpX[4];
  int lbX[4];
#pragma unroll
  for (int j = 0; j < 4; ++j) {
    const int r = wv * 32 + j * 8 + lr;  // 0..127
    const int gm = min(mt * 128 + r, cnt - 1);
    const int t = perm[off + gm] >> 1;  // TOPK=2
    gpX[j] = x + (size_t)t * DDIM + ((lc ^ (r & 7)) << 2);
    lbX[j] = (wv * 32 + j * 8) * 32;
  }
  const float* gpG[2];
  const float* gpU[2];
  int lbW[2];
#pragma unroll
  for (int j = 0; j < 2; ++j) {
    const int r = wv * 16 + j * 8 + lr;  // 0..63
    const size_t row = (size_t)e * HDIM + nt * 64 + r;
    gpG[j] = wg + row * DDIM + ((lc ^ (r & 7)) << 2);
    gpU[j] = wu + row * DDIM + ((lc ^ (r & 7)) << 2);
    lbW[j] = (wv * 16 + j * 8) * 32;
  }

  f32x4 aG[4][2] = {};
  f32x4 aU[4][2] = {};

#define S1_STAGE(b) do {                                     \
    _Pragma("unroll") for (int j = 0; j < 4; ++j)            \
      gl16(gpX[j], &sX[b][lbX[j]]);                          \
    _Pragma("unroll") for (int j = 0; j < 2; ++j) {          \
      gl16(gpG[j], &sG[b][lbW[j]]);                          \
      gl16(gpU[j], &sU[b][lbW[j]]);                          \
    }                                                        \
    _Pragma("unroll") for (int j = 0; j < 4; ++j) gpX[j] += 32; \
    _Pragma("unroll") for (int j = 0; j < 2; ++j) { gpG[j] += 32; gpU[j] += 32; } \
  } while (0)

#define RD8(tile, r_, kb_) cvt8(                                            \
    *(const float4*)&(tile)[(r_) * 32 + ((((kb_) * 2    ) ^ ((r_) & 7)) << 2)], \
    *(const float4*)&(tile)[(r_) * 32 + ((((kb_) * 2 + 1) ^ ((r_) & 7)) << 2)])

#define S1_COMPUTE(b) do {                                   \
    const int fr_ = lane & 15, kb_ = lane >> 4;              \
    bf16x8 a_[4], g_[2], u_[2];                              \
    _Pragma("unroll") for (int mi = 0; mi < 4; ++mi)         \
      a_[mi] = RD8(sX[b], wm + mi * 16 + fr_, kb_);          \
    _Pragma("unroll") for (int nj = 0; nj < 2; ++nj) {       \
      g_[nj] = RD8(sG[b], wn + nj * 16 + fr_, kb_);          \
      u_[nj] = RD8(sU[b], wn + nj * 16 + fr_, kb_);          \
    }                                                        \
    _Pragma("unroll") for (int mi = 0; mi < 4; ++mi)         \
      _Pragma("unroll") for (int nj = 0; nj < 2; ++nj) {     \
        aG[mi][nj] = mfma(a_[mi], g_[nj], aG[mi][nj]);       \
        aU[mi][nj] = mfma(a_[mi], u_[nj], aU[mi][nj]);       \
      }                                                      \
  } while (0)

  S1_STAGE(0);
  phase_sync();
#pragma unroll 1
  for (int kt = 0; kt < 24; ++kt) {
    const int cb = kt & 1;
    if (kt + 1 < 24) S1_STAGE(cb ^ 1);
    __builtin_amdgcn_sched_barrier(0);
    S1_COMPUTE(cb);
    phase_sync();
  }

  // epilogue: C/D layout col=lane&15, row=(lane>>4)*4+reg
  const int crow = (lane >> 4) << 2;
  const int ccol = lane & 15;
#pragma unroll
  for (int mi = 0; mi < 4; ++mi) {
#pragma unroll
    for (int ri = 0; ri < 4; ++ri) {
      const int gm = mt * 128 + wm + mi * 16 + crow + ri;
      if (gm < cnt) {
        u16* hb = hbuf + (size_t)(off + gm) * HDIM + nt * 64 + wn;
#pragma unroll
        for (int nj = 0; nj < 2; ++nj) {
          const float g = aG[mi][nj][ri];
          const float u = aU[mi][nj][ri];
          const float h = g / (1.0f + __expf(-g)) * u;
          hb[nj * 16 + ccol] = f2bf(h);
        }
      }
    }
  }
}

// ---------------------------------------------------------------------------
// Stage 2: out[tok,:] += h Wd^T.  BM=128, BN=64, BK=32, split-K=2.
// grid (12, 32, 8): by -> mt = by&15, ks = by>>4. 256 thr = 4 waves 2Mx2N.
// ---------------------------------------------------------------------------
__global__ __launch_bounds__(256, 2) void moe_stage2(
    const u16* __restrict__ hbuf, const int* __restrict__ perm,
    const int* __restrict__ offs, const float* __restrict__ wd,
    float* __restrict__ out) {
  const int e = blockIdx.z;
  const int off = offs[e];
  const int cnt = offs[e + 1] - off;
  const int mt = blockIdx.y & 15;
  const int ks = blockIdx.y >> 4;
  if (mt * 128 >= cnt) return;
  const int nt = blockIdx.x;  // 0..11

  __shared__ __align__(16) u16  sA[2][128 * 32];
  __shared__ __align__(16) float sB[2][64 * 32];

  const int tid = threadIdx.x;
  const int lane = tid & 63;
  const int wv = tid >> 6;
  const int wm = (wv >> 1) * 64;
  const int wn = (wv & 1) * 32;

  // A (bf16): rows are 64B = 4 chunks of 16B; lane L -> (row L>>2, chunk L&3);
  // global chunk = (L&3) ^ ((row>>1)&3).
  const u16* gpA[2];
  int lbA[2];
#pragma unroll
  for (int j = 0; j < 2; ++j) {
    const int r = wv * 32 + j * 16 + (lane >> 2);  // 0..127
    const int gm = min(mt * 128 + r, cnt - 1);
    gpA[j] = hbuf + (size_t)(off + gm) * HDIM + ks * 1024 +
             (((lane & 3) ^ ((r >> 1) & 3)) << 3);
    lbA[j] = (wv * 32 + j * 16) * 32;
  }
  // B (fp32): as stage1 weights
  const float* gpB[2];
  int lbB[2];
#pragma unroll
  for (int j = 0; j < 2; ++j) {
    const int r = wv * 16 + j * 8 + (lane >> 3);  // 0..63
    gpB[j] = wd + ((size_t)e * DDIM + nt * 64 + r) * HDIM + ks * 1024 +
             (((lane & 7) ^ (r & 7)) << 2);
    lbB[j] = (wv * 16 + j * 8) * 32;
  }

  f32x4 acc[4][2] = {};

#define S2_STAGE(b) do {                                     \
    _Pragma("unroll") for (int j = 0; j < 2; ++j) {          \
      gl16(gpA[j], &sA[b][lbA[j]]);                          \
      gl16(gpB[j], &sB[b][lbB[j]]);                          \
    }                                                        \
    _Pragma("unroll") for (int j = 0; j < 2; ++j) { gpA[j] += 32; gpB[j] += 32; } \
  } while (0)

#define S2_COMPUTE(b) do {                                   \
    const int fr_ = lane & 15, kb_ = lane >> 4;              \
    bf16x8 a_[4], b_[2];                                     \
    _Pragma("unroll") for (int mi = 0; mi < 4; ++mi) {       \
      const int r_ = wm + mi * 16 + fr_;                     \
      a_[mi] = fragb(&sA[b][r_ * 32 + ((kb_ ^ ((r_ >> 1) & 3)) << 3)]); \
    }                                                        \
    _Pragma("unroll") for (int nj = 0; nj < 2; ++nj)         \
      b_[nj] = RD8(sB[b], wn + nj * 16 + fr_, kb_);          \
    _Pragma("unroll") for (int mi = 0; mi < 4; ++mi)         \
      _Pragma("unroll") for (int nj = 0; nj < 2; ++nj)       \
        acc[mi][nj] = mfma(a_[mi], b_[nj], acc[mi][nj]);     \
  } while (0)

  S2_STAGE(0);
  phase_sync();
#pragma unroll 1
  for (int kt = 0; kt < 32; ++kt) {
    const int cb = kt & 1;
    if (kt + 1 < 32) S2_STAGE(cb ^ 1);
    __builtin_amdgcn_sched_barrier(0);
    S2_COMPUTE(cb);
    phase_sync();
  }

  const int crow = (lane >> 4) << 2;
  const int ccol = lane & 15;
#pragma unroll
  for (int mi = 0; mi < 4; ++mi) {
#pragma unroll
    for (int ri = 0; ri < 4; ++ri) {
      const int gm = mt * 128 + wm + mi * 16 + crow + ri;
      if (gm < cnt) {
        const int t = perm[off + gm];
        float* orow = out + (size_t)t * DDIM + nt * 64 + wn;
#pragma unroll
        for (int nj = 0; nj < 2; ++nj) {
          atomicAdd(&orow[nj * 16 + ccol], acc[mi][nj][ri]);
        }
      }
    }
  }
}

// ---------------------------------------------------------------------------
extern "C" void kernel_launch(void* const* d_in, const int* in_sizes, int n_in,
                              void* d_out, int out_size, void* d_ws, size_t ws_size,
                              hipStream_t stream) {
  const float* x  = (const float*)d_in[0];
  const int* idx  = (const int*)d_in[1];
  const float* wg = (const float*)d_in[2];
  const float* wu = (const float*)d_in[3];
  const float* wd = (const float*)d_in[4];
  float* out = (float*)d_out;

  int* iws = (int*)d_ws;
  int* offs = iws;       // 9 ints
  int* perm = iws + 16;  // 2048 ints
  u16* hbuf = (u16*)((char*)d_ws + 16384);  // 2048*2048 bf16 = 8 MB

  hipMemsetAsync(d_out, 0, (size_t)out_size * sizeof(float), stream);
  moe_dispatch<<<1, 256, 0, stream>>>(idx, offs, perm);
  moe_stage1<<<dim3(32, 16, NE), 256, 0, stream>>>(x, perm, offs, wg, wu, hbuf);
  moe_stage2<<<dim3(12, 32, NE), 256, 0, stream>>>(hbuf, perm, offs, wd, out);
}

// Round 5
// 105.619 us; speedup vs baseline: 1.1885x; 1.0975x over previous
//
#include <hip/hip_runtime.h>

// ---------------------------------------------------------------------------
// SwitchGLU MoE, round 5: dense 1-D grids via device-side tile table.
//  - moe_dispatch builds a packed list of 128-row M-tiles (real tiles first)
//    -> active blocks are contiguous low block-ids -> spread over all 256 CUs
//    (R1-R4 grids aliased all active blocks onto CUs 0..63: 4x loss)
//  - global_load_lds staging, 2-phase schedule, vmcnt(0)+barrier per phase
//  - fp32->bf16 via plain casts (v_cvt_pk_bf16_f32), not perm-pack
//  - stage2: BM=128/BN=64/BK=32, split-K=2, deterministic 2-addend atomicAdd
// ---------------------------------------------------------------------------

typedef unsigned short u16;
typedef unsigned int   u32;
typedef u16    u16x8 __attribute__((ext_vector_type(8)));
typedef __bf16 bf16x8 __attribute__((ext_vector_type(8)));
typedef float  f32x4 __attribute__((ext_vector_type(4)));

#define NE   8
#define DDIM 768
#define HDIM 2048
#define NTOT 2048
#define MAXT 24   // >= max tiles: floor(2048/128) + (NE-1) = 23

__device__ __forceinline__ u16 f2bf(float f) {
  return (u16)((__builtin_bit_cast(u32, f) + 0x8000u) >> 16);
}
// 8x fp32 -> bf16x8 via casts (compiler emits v_cvt_pk_bf16_f32)
__device__ __forceinline__ bf16x8 cvt8(float4 a, float4 b) {
  bf16x8 r;
  r[0] = (__bf16)a.x; r[1] = (__bf16)a.y; r[2] = (__bf16)a.z; r[3] = (__bf16)a.w;
  r[4] = (__bf16)b.x; r[5] = (__bf16)b.y; r[6] = (__bf16)b.z; r[7] = (__bf16)b.w;
  return r;
}
__device__ __forceinline__ bf16x8 fragb(const u16* p) {
  return __builtin_bit_cast(bf16x8, *reinterpret_cast<const u16x8*>(p));
}
__device__ __forceinline__ f32x4 mfma(bf16x8 a, bf16x8 b, f32x4 c) {
  return __builtin_amdgcn_mfma_f32_16x16x32_bf16(a, b, c, 0, 0, 0);
}
__device__ __forceinline__ void gl16(const void* g, void* l) {
  __builtin_amdgcn_global_load_lds(
      (const __attribute__((address_space(1))) void*)g,
      (__attribute__((address_space(3))) void*)l, 16, 0, 0);
}
__device__ __forceinline__ void phase_sync() {
  __builtin_amdgcn_sched_barrier(0);
  asm volatile("s_waitcnt vmcnt(0) lgkmcnt(0)" ::: "memory");
  __builtin_amdgcn_s_barrier();
  __builtin_amdgcn_sched_barrier(0);
}

// ---------------------------------------------------------------------------
// Dispatch: bucket token-pairs by expert + build 128-row tile table.
// meta[0..8]=offs, meta[15]=ntiles, meta[16+t]=expert, meta[48+t]=row0.
// ---------------------------------------------------------------------------
__global__ void moe_dispatch(const int* __restrict__ idx,
                             int* __restrict__ meta, int* __restrict__ perm) {
  __shared__ int s_cnt[NE];
  __shared__ int s_off[NE + 1];
  __shared__ int s_cur[NE];
  const int tid = threadIdx.x;
  if (tid < NE) { s_cnt[tid] = 0; s_cur[tid] = 0; }
  __syncthreads();
  for (int n = tid; n < NTOT; n += 256) atomicAdd(&s_cnt[idx[n]], 1);
  __syncthreads();
  if (tid == 0) {
    int a = 0;
    for (int e = 0; e < NE; ++e) { s_off[e] = a; a += s_cnt[e]; }
    s_off[NE] = a;
  }
  __syncthreads();
  for (int n = tid; n < NTOT; n += 256) {
    const int e = idx[n];
    perm[s_off[e] + atomicAdd(&s_cur[e], 1)] = n;
  }
  if (tid == 0) {
    int tc = 0;
    for (int e = 0; e < NE; ++e) {
      for (int r0 = s_off[e]; r0 < s_off[e + 1]; r0 += 128) {
        meta[16 + tc] = e;
        meta[48 + tc] = r0;
        ++tc;
      }
    }
    meta[15] = tc;
  }
  if (tid < NE + 1) meta[tid] = s_off[tid];
}

// ---------------------------------------------------------------------------
// Stage 1: h = silu(X Wg^T) * (X Wu^T).  BM=128, BN=64(G)+64(U), BK=32.
// grid = MAXT*32 flat: bid = tile*32 + nt.  256 thr = 4 waves (2M x 2N),
// wave = 64M x 32N of both G and U.
// ---------------------------------------------------------------------------
__global__ __launch_bounds__(256, 2) void moe_stage1(
    const float* __restrict__ x, const int* __restrict__ perm,
    const int* __restrict__ meta, const float* __restrict__ wg,
    const float* __restrict__ wu, u16* __restrict__ hbuf) {
  const int t = blockIdx.x >> 5;
  if (t >= meta[15]) return;
  const int nt = blockIdx.x & 31;  // 0..31 (H columns nt*64)
  const int e = meta[16 + t];
  const int r0 = meta[48 + t];
  const int rows = min(128, meta[e + 1] - r0);

  __shared__ __align__(16) float sX[2][128 * 32];
  __shared__ __align__(16) float sG[2][64 * 32];
  __shared__ __align__(16) float sU[2][64 * 32];

  const int tid = threadIdx.x;
  const int lane = tid & 63;
  const int wv = tid >> 6;
  const int wm = (wv >> 1) * 64;  // 0,64
  const int wn = (wv & 1) * 32;   // 0,32

  // staging: fp32 rows = 8 chunks of 16B; lane L -> (row L>>3, chunk L&7),
  // source chunk pre-swizzled: (L&7) ^ (row&7); LDS dest linear (lane*16).
  const int lr = lane >> 3, lc = lane & 7;
  const float* gpX[4];
  int lbX[4];
#pragma unroll
  for (int j = 0; j < 4; ++j) {
    const int r = wv * 32 + j * 8 + lr;
    const int tok = perm[r0 + min(r, rows - 1)] >> 1;  // TOPK=2
    gpX[j] = x + (size_t)tok * DDIM + ((lc ^ (r & 7)) << 2);
    lbX[j] = (wv * 32 + j * 8) * 32;
  }
  const float* gpG[2];
  const float* gpU[2];
  int lbW[2];
#pragma unroll
  for (int j = 0; j < 2; ++j) {
    const int r = wv * 16 + j * 8 + lr;
    const size_t row = (size_t)e * HDIM + nt * 64 + r;
    gpG[j] = wg + row * DDIM + ((lc ^ (r & 7)) << 2);
    gpU[j] = wu + row * DDIM + ((lc ^ (r & 7)) << 2);
    lbW[j] = (wv * 16 + j * 8) * 32;
  }

  f32x4 aG[4][2] = {};
  f32x4 aU[4][2] = {};

#define S1_STAGE(b) do {                                     \
    _Pragma("unroll") for (int j = 0; j < 4; ++j)            \
      gl16(gpX[j], &sX[b][lbX[j]]);                          \
    _Pragma("unroll") for (int j = 0; j < 2; ++j) {          \
      gl16(gpG[j], &sG[b][lbW[j]]);                          \
      gl16(gpU[j], &sU[b][lbW[j]]);                          \
    }                                                        \
    _Pragma("unroll") for (int j = 0; j < 4; ++j) gpX[j] += 32; \
    _Pragma("unroll") for (int j = 0; j < 2; ++j) { gpG[j] += 32; gpU[j] += 32; } \
  } while (0)

#define RD8(tile, r_, kb_) cvt8(                                            \
    *(const float4*)&(tile)[(r_) * 32 + ((((kb_) * 2    ) ^ ((r_) & 7)) << 2)], \
    *(const float4*)&(tile)[(r_) * 32 + ((((kb_) * 2 + 1) ^ ((r_) & 7)) << 2)])

#define S1_COMPUTE(b) do {                                   \
    const int fr_ = lane & 15, kb_ = lane >> 4;              \
    bf16x8 a_[4], g_[2], u_[2];                              \
    _Pragma("unroll") for (int mi = 0; mi < 4; ++mi)         \
      a_[mi] = RD8(sX[b], wm + mi * 16 + fr_, kb_);          \
    _Pragma("unroll") for (int nj = 0; nj < 2; ++nj) {       \
      g_[nj] = RD8(sG[b], wn + nj * 16 + fr_, kb_);          \
      u_[nj] = RD8(sU[b], wn + nj * 16 + fr_, kb_);          \
    }                                                        \
    _Pragma("unroll") for (int mi = 0; mi < 4; ++mi)         \
      _Pragma("unroll") for (int nj = 0; nj < 2; ++nj) {     \
        aG[mi][nj] = mfma(a_[mi], g_[nj], aG[mi][nj]);       \
        aU[mi][nj] = mfma(a_[mi], u_[nj], aU[mi][nj]);       \
      }                                                      \
  } while (0)

  S1_STAGE(0);
  phase_sync();
#pragma unroll 1
  for (int kt = 0; kt < 24; ++kt) {
    const int cb = kt & 1;
    if (kt + 1 < 24) S1_STAGE(cb ^ 1);
    __builtin_amdgcn_sched_barrier(0);
    S1_COMPUTE(cb);
    phase_sync();
  }

  // epilogue: C/D layout col=lane&15, row=(lane>>4)*4+reg
  const int crow = (lane >> 4) << 2;
  const int ccol = lane & 15;
#pragma unroll
  for (int mi = 0; mi < 4; ++mi) {
#pragma unroll
    for (int ri = 0; ri < 4; ++ri) {
      const int lm = wm + mi * 16 + crow + ri;
      if (lm < rows) {
        u16* hb = hbuf + (size_t)(r0 + lm) * HDIM + nt * 64 + wn;
#pragma unroll
        for (int nj = 0; nj < 2; ++nj) {
          const float g = aG[mi][nj][ri];
          const float u = aU[mi][nj][ri];
          const float h = g / (1.0f + __expf(-g)) * u;
          hb[nj * 16 + ccol] = f2bf(h);
        }
      }
    }
  }
}

// ---------------------------------------------------------------------------
// Stage 2: out[tok,:] += h Wd^T.  BM=128, BN=64, BK=32, split-K=2.
// grid = MAXT*24 flat: bid = tile*24 + ks*12 + nt.  256 thr, 4 waves 2M x 2N.
// ---------------------------------------------------------------------------
__global__ __launch_bounds__(256, 4) void moe_stage2(
    const u16* __restrict__ hbuf, const int* __restrict__ perm,
    const int* __restrict__ meta, const float* __restrict__ wd,
    float* __restrict__ out) {
  const int t = blockIdx.x / 24;
  if (t >= meta[15]) return;
  const int rem = blockIdx.x - t * 24;
  const int ks = rem / 12;          // 0..1
  const int nt = rem - ks * 12;     // 0..11 (D columns nt*64)
  const int e = meta[16 + t];
  const int r0 = meta[48 + t];
  const int rows = min(128, meta[e + 1] - r0);

  __shared__ __align__(16) u16   sA[2][128 * 32];
  __shared__ __align__(16) float sB[2][64 * 32];

  const int tid = threadIdx.x;
  const int lane = tid & 63;
  const int wv = tid >> 6;
  const int wm = (wv >> 1) * 64;
  const int wn = (wv & 1) * 32;

  // A (bf16): rows = 4 chunks of 16B; lane L -> (row L>>2, chunk L&3),
  // source chunk (L&3) ^ ((row>>1)&3).
  const u16* gpA[2];
  int lbA[2];
#pragma unroll
  for (int j = 0; j < 2; ++j) {
    const int r = wv * 32 + j * 16 + (lane >> 2);
    gpA[j] = hbuf + (size_t)(r0 + min(r, rows - 1)) * HDIM + ks * 1024 +
             (((lane & 3) ^ ((r >> 1) & 3)) << 3);
    lbA[j] = (wv * 32 + j * 16) * 32;
  }
  // B (fp32): as stage1 weights.
  const float* gpB[2];
  int lbB[2];
#pragma unroll
  for (int j = 0; j < 2; ++j) {
    const int r = wv * 16 + j * 8 + (lane >> 3);
    gpB[j] = wd + ((size_t)e * DDIM + nt * 64 + r) * HDIM + ks * 1024 +
             (((lane & 7) ^ (r & 7)) << 2);
    lbB[j] = (wv * 16 + j * 8) * 32;
  }

  f32x4 acc[4][2] = {};

#define S2_STAGE(b) do {                                     \
    _Pragma("unroll") for (int j = 0; j < 2; ++j) {          \
      gl16(gpA[j], &sA[b][lbA[j]]);                          \
      gl16(gpB[j], &sB[b][lbB[j]]);                          \
    }                                                        \
    _Pragma("unroll") for (int j = 0; j < 2; ++j) { gpA[j] += 32; gpB[j] += 32; } \
  } while (0)

#define S2_COMPUTE(b) do {                                   \
    const int fr_ = lane & 15, kb_ = lane >> 4;              \
    bf16x8 a_[4], b_[2];                                     \
    _Pragma("unroll") for (int mi = 0; mi < 4; ++mi) {       \
      const int r_ = wm + mi * 16 + fr_;                     \
      a_[mi] = fragb(&sA[b][r_ * 32 + ((kb_ ^ ((r_ >> 1) & 3)) << 3)]); \
    }                                                        \
    _Pragma("unroll") for (int nj = 0; nj < 2; ++nj)         \
      b_[nj] = RD8(sB[b], wn + nj * 16 + fr_, kb_);          \
    _Pragma("unroll") for (int mi = 0; mi < 4; ++mi)         \
      _Pragma("unroll") for (int nj = 0; nj < 2; ++nj)       \
        acc[mi][nj] = mfma(a_[mi], b_[nj], acc[mi][nj]);     \
  } while (0)

  S2_STAGE(0);
  phase_sync();
#pragma unroll 1
  for (int kt = 0; kt < 32; ++kt) {
    const int cb = kt & 1;
    if (kt + 1 < 32) S2_STAGE(cb ^ 1);
    __builtin_amdgcn_sched_barrier(0);
    S2_COMPUTE(cb);
    phase_sync();
  }

  const int crow = (lane >> 4) << 2;
  const int ccol = lane & 15;
#pragma unroll
  for (int mi = 0; mi < 4; ++mi) {
#pragma unroll
    for (int ri = 0; ri < 4; ++ri) {
      const int lm = wm + mi * 16 + crow + ri;
      if (lm < rows) {
        const int tok = perm[r0 + lm];
        float* orow = out + (size_t)tok * DDIM + nt * 64 + wn;
#pragma unroll
        for (int nj = 0; nj < 2; ++nj) {
          atomicAdd(&orow[nj * 16 + ccol], acc[mi][nj][ri]);
        }
      }
    }
  }
}

// ---------------------------------------------------------------------------
extern "C" void kernel_launch(void* const* d_in, const int* in_sizes, int n_in,
                              void* d_out, int out_size, void* d_ws, size_t ws_size,
                              hipStream_t stream) {
  const float* x  = (const float*)d_in[0];
  const int* idx  = (const int*)d_in[1];
  const float* wg = (const float*)d_in[2];
  const float* wu = (const float*)d_in[3];
  const float* wd = (const float*)d_in[4];
  float* out = (float*)d_out;

  int* iws = (int*)d_ws;
  int* meta = iws;        // [0..8] offs, [15] ntiles, [16..47] e, [48..79] r0
  int* perm = iws + 128;  // 2048 ints
  u16* hbuf = (u16*)((char*)d_ws + 16384);  // 2048*2048 bf16 = 8 MB

  hipMemsetAsync(d_out, 0, (size_t)out_size * sizeof(float), stream);
  moe_dispatch<<<1, 256, 0, stream>>>(idx, meta, perm);
  moe_stage1<<<MAXT * 32, 256, 0, stream>>>(x, perm, meta, wg, wu, hbuf);
  moe_stage2<<<MAXT * 24, 256, 0, stream>>>(hbuf, perm, meta, wd, out);
}